// Round 1
// baseline (136.755 us; speedup 1.0000x reference)
//
#include <hip/hip_runtime.h>
#include <math.h>

#define CHUNK 32   // rows per chunk; NC = T/32 = 48 for T=1536

// ---------------- K1: fused q/k/v projections, 2 batches per block ----------------
// grid (D, B/2), block 64. One wave computes q/k/v[d] for batches b0,b0+1.
// W rows are the dominant L2 traffic; amortizing each W row over 2 batches
// cuts block traffic from 64KB to 80KB per 2 outputs (262MB -> 164MB total).
__global__ void proj_kernel(const float* __restrict__ x,
                            const float* __restrict__ Wq,
                            const float* __restrict__ Wk,
                            const float* __restrict__ Wv,
                            float* __restrict__ qkv, // [3][B][D]
                            int B, int E, int D)
{
    int d  = blockIdx.x;
    int b0 = blockIdx.y * 2;
    int b1 = b0 + 1;
    bool has_b1 = (b1 < B);
    int lane = threadIdx.x; // 0..63
    const float* x0 = x + (size_t)b0 * E;
    const float* x1 = x + (size_t)(has_b1 ? b1 : b0) * E;
    size_t woff = (size_t)d * E;
    float aq0 = 0.f, ak0 = 0.f, av0 = 0.f;
    float aq1 = 0.f, ak1 = 0.f, av1 = 0.f;
    for (int i = lane * 4; i < E; i += 64 * 4) {   // 16 iters at E=4096
        float4 q4 = *(const float4*)(Wq + woff + i);
        float4 k4 = *(const float4*)(Wk + woff + i);
        float4 v4 = *(const float4*)(Wv + woff + i);
        float4 xa = *(const float4*)(x0 + i);
        float4 xb = *(const float4*)(x1 + i);
        aq0 += xa.x*q4.x + xa.y*q4.y + xa.z*q4.z + xa.w*q4.w;
        ak0 += xa.x*k4.x + xa.y*k4.y + xa.z*k4.z + xa.w*k4.w;
        av0 += xa.x*v4.x + xa.y*v4.y + xa.z*v4.z + xa.w*v4.w;
        aq1 += xb.x*q4.x + xb.y*q4.y + xb.z*q4.z + xb.w*q4.w;
        ak1 += xb.x*k4.x + xb.y*k4.y + xb.z*k4.z + xb.w*k4.w;
        av1 += xb.x*v4.x + xb.y*v4.y + xb.z*v4.z + xb.w*v4.w;
    }
    #pragma unroll
    for (int off = 32; off >= 1; off >>= 1) {
        aq0 += __shfl_xor(aq0, off, 64);
        ak0 += __shfl_xor(ak0, off, 64);
        av0 += __shfl_xor(av0, off, 64);
        aq1 += __shfl_xor(aq1, off, 64);
        ak1 += __shfl_xor(ak1, off, 64);
        av1 += __shfl_xor(av1, off, 64);
    }
    if (lane == 0) {
        qkv[(size_t)b0 * D + d] = aq0;
        qkv[((size_t)B + b0) * D + d] = ak0;
        qkv[((size_t)2 * B + b0) * D + d] = av0;
        if (has_b1) {
            qkv[(size_t)b1 * D + d] = aq1;
            qkv[((size_t)B + b1) * D + d] = ak1;
            qkv[((size_t)2 * B + b1) * D + d] = av1;
        }
    }
}

// ---------------- K2: scores + per-chunk online-softmax partials ----------------
// grid (NC, B), block 256 (4 waves). Unchanged from verified version.
__global__ void score_chunk_kernel(const float* __restrict__ kv,  // [2][B][MT][D]
                                   const float* __restrict__ qkv, // [3][B][D]
                                   const int* __restrict__ next_pos,
                                   float* __restrict__ s_out,     // [B][T]
                                   float* __restrict__ m_out,     // [B][NC]
                                   float* __restrict__ l_out,     // [B][NC]
                                   float* __restrict__ acc_out,   // [B][NC][D]
                                   int B, int D, int T, int MT, int NC, float scale)
{
    int c = blockIdx.x;
    int b = blockIdx.y;
    int tid = threadIdx.x;   // 0..255
    int wave = tid >> 6;
    int lane = tid & 63;
    int l16 = lane & 15;     // position within 16-lane row group
    int g16 = lane >> 4;     // row group 0..3 within wave

    __shared__ float s_sh[CHUNK];
    __shared__ float w_sh[CHUNK];
    __shared__ float part[8][128];

    int np = next_pos[b];
    int t0 = c * CHUNK;
    const float* q    = qkv + (size_t)b * D;
    const float* knew = qkv + ((size_t)B + b) * D;
    const float* kbase = kv + (size_t)b * MT * D;
    const float4* vnew4 = (const float4*)(qkv + ((size_t)2 * B + b) * D);
    const float4* vbase4 = (const float4*)(kv + ((size_t)B + b) * MT * D);

    // q fragment: 8 floats/lane (d = l16*8 .. +8), L2-hot
    float4 qa = *(const float4*)(q + l16 * 8);
    float4 qb = *(const float4*)(q + l16 * 8 + 4);

    // scores: wave handles rows [wave*8, wave*8+8) in 2 passes of 4 rows
    #pragma unroll
    for (int p = 0; p < 2; ++p) {
        int j = wave * 8 + p * 4 + g16;
        int t = t0 + j;
        const float* krow = (t == np) ? knew : (kbase + (size_t)t * D);
        float4 ka = *(const float4*)(krow + l16 * 8);
        float4 kb = *(const float4*)(krow + l16 * 8 + 4);
        float ps = qa.x*ka.x + qa.y*ka.y + qa.z*ka.z + qa.w*ka.w
                 + qb.x*kb.x + qb.y*kb.y + qb.z*kb.z + qb.w*kb.w;
        ps += __shfl_xor(ps, 1, 64);
        ps += __shfl_xor(ps, 2, 64);
        ps += __shfl_xor(ps, 4, 64);
        ps += __shfl_xor(ps, 8, 64);
        if (l16 == 0) {
            float sv = (t < T) ? ps * scale : -1e30f;
            s_sh[j] = sv;
            if (t < T) s_out[(size_t)b * T + t] = sv;
        }
    }
    __syncthreads();

    // wave 0: chunk max, weights, weight-sum (32 scores, duplicated per half)
    if (wave == 0) {
        float sv = s_sh[lane & 31];
        float m = sv;
        #pragma unroll
        for (int off = 16; off >= 1; off >>= 1)
            m = fmaxf(m, __shfl_xor(m, off, 64));
        float w = __expf(sv - m);
        w_sh[lane & 31] = w;
        float l = w;
        #pragma unroll
        for (int off = 16; off >= 1; off >>= 1)
            l += __shfl_xor(l, off, 64);
        if (lane == 0) {
            m_out[(size_t)b * NC + c] = m;
            l_out[(size_t)b * NC + c] = l;
        }
    }
    __syncthreads();

    // v accumulation: 8 row-groups x 32 float4-columns, float4 loads
    int rg = tid >> 5;       // 0..7 (4 rows each)
    int d4 = tid & 31;       // float4 column
    float4 a4 = make_float4(0.f, 0.f, 0.f, 0.f);
    #pragma unroll
    for (int p = 0; p < 4; ++p) {
        int j = rg * 4 + p;
        int t = t0 + j;
        float4 vv = (t == np) ? vnew4[d4] : vbase4[(size_t)t * 32 + d4];
        float w = w_sh[j];
        a4.x += w * vv.x; a4.y += w * vv.y; a4.z += w * vv.z; a4.w += w * vv.w;
    }
    ((float4*)&part[rg][d4 * 4])[0] = a4;
    __syncthreads();
    if (tid < 128) {
        float s = 0.f;
        #pragma unroll
        for (int r = 0; r < 8; ++r) s += part[r][tid];
        acc_out[((size_t)b * NC + c) * D + tid] = s;
    }
}

// ---------------- K3: self-scan + per-chunk prefix outputs ----------------
// grid (NC, B), block 256. Lower 128 threads: redundant cross-chunk scan
// (replaces the separate 32-block scan kernel; <=47 coalesced L2-hot reads
// of 512B each) then prefix stream; upper 128 threads: stage v concurrently.
__global__ void out_kernel(const float* __restrict__ kv,
                           const float* __restrict__ qkv,
                           const int* __restrict__ next_pos,
                           const float* __restrict__ s_in,   // [B][T]
                           const float* __restrict__ m_in,   // [B][NC]
                           const float* __restrict__ l_in,   // [B][NC]
                           const float* __restrict__ acc_in, // [B][NC][D]
                           float* __restrict__ out,          // [B][T][D]
                           int B, int D, int T, int MT, int NC)
{
    int c = blockIdx.x;
    int b = blockIdx.y;
    int tid = threadIdx.x; // 0..255

    __shared__ float vs[CHUNK * 128];  // 16 KB staged v rows
    __shared__ float w_sh[CHUNK];
    __shared__ float rl_sh[CHUNK];

    int np = next_pos[b];
    int t0 = c * CHUNK;

    const float4* vnew4 = (const float4*)(qkv + ((size_t)2 * B + b) * D);
    const float4* vbase4 = (const float4*)(kv + ((size_t)B + b) * MT * D);

    float A = 0.f, L = 0.f, M = -1e30f;
    if (tid < 128) {
        // exclusive online-softmax scan over chunks 0..c-1 (same recurrence
        // as the old scan kernel; L/M tracked redundantly per thread)
        const float* mrow = m_in + (size_t)b * NC;
        const float* lrow = l_in + (size_t)b * NC;
        const float* arow = acc_in + ((size_t)b * NC) * D + tid;
        for (int cc = 0; cc < c; ++cc) {
            float mc = mrow[cc];
            float Mn = fmaxf(M, mc);
            float eo = __expf(M - Mn);
            float ec = __expf(mc - Mn);
            A = A * eo + ec * arow[(size_t)cc * D];
            L = L * eo + ec * lrow[cc];
            M = Mn;
        }
        // fold in this chunk's block max -> inclusive M, rescaled carries
        float mc = mrow[c];
        float Mn = fmaxf(M, mc);
        float eo = __expf(M - Mn);
        A *= eo; L *= eo; M = Mn;
        if (tid < CHUNK) {
            int t = t0 + tid;
            w_sh[tid] = (t < T) ? __expf(s_in[(size_t)b * T + t] - M) : 0.f;
        }
    } else {
        // stage v rows (coalesced float4), overlapped with the scan above
        int t2 = tid - 128;
        #pragma unroll
        for (int r = 0; r < 8; ++r) {
            int i4 = t2 + r * 128;            // 0..1023 float4 slots
            int j = i4 >> 5;                  // row (32 float4 per row)
            int t = t0 + j;
            float4 vv = (t == np) ? vnew4[i4 & 31]
                                  : vbase4[(size_t)t * 32 + (i4 & 31)];
            ((float4*)vs)[i4] = vv;
        }
    }
    __syncthreads();

    // per-row reciprocal denominators (32 parallel divides; L valid on tid<32)
    if (tid < CHUNK) {
        float Lr = L;
        for (int r = 0; r <= tid; ++r)
            Lr += w_sh[r];
        rl_sh[tid] = 1.0f / Lr;
    }
    __syncthreads();

    // prefix stream from LDS, coalesced stores
    if (tid < 128) {
        float* orow = out + ((size_t)b * T + t0) * (size_t)D + tid;
        #pragma unroll
        for (int j = 0; j < CHUNK; ++j) {
            int t = t0 + j;
            if (t >= T) break;
            A += w_sh[j] * vs[j * 128 + tid];
            orow[(size_t)j * D] = A * rl_sh[j];
        }
    }
}

extern "C" void kernel_launch(void* const* d_in, const int* in_sizes, int n_in,
                              void* d_out, int out_size, void* d_ws, size_t ws_size,
                              hipStream_t stream) {
    const float* x        = (const float*)d_in[0];
    const float* Wq       = (const float*)d_in[1];
    const float* Wk       = (const float*)d_in[2];
    const float* Wv       = (const float*)d_in[3];
    const float* kv       = (const float*)d_in[4];
    const int*   next_pos = (const int*)d_in[5];
    float* out = (float*)d_out;

    const int B  = in_sizes[5];                 // 32
    const int E  = in_sizes[0] / B;             // 4096
    const int D  = in_sizes[1] / E;             // 128
    const int T  = out_size / (B * D);          // 1536
    const int MT = in_sizes[4] / (2 * B * D);   // 2048
    const int NC = (T + CHUNK - 1) / CHUNK;     // 48

    float* ws  = (float*)d_ws;
    float* qkv = ws;                            // 3*B*D
    float* s   = qkv + (size_t)3 * B * D;       // B*T
    float* m   = s + (size_t)B * T;             // B*NC
    float* l   = m + (size_t)B * NC;            // B*NC
    float* acc = l + (size_t)B * NC;            // B*NC*D

    const float scale = 1.0f / sqrtf((float)D);

    proj_kernel<<<dim3(D, (B + 1) / 2), 64, 0, stream>>>(x, Wq, Wk, Wv, qkv, B, E, D);
    score_chunk_kernel<<<dim3(NC, B), 256, 0, stream>>>(kv, qkv, next_pos,
                                                        s, m, l, acc,
                                                        B, D, T, MT, NC, scale);
    out_kernel<<<dim3(NC, B), 256, 0, stream>>>(kv, qkv, next_pos,
                                                s, m, l, acc, out,
                                                B, D, T, MT, NC);
}